// Round 12
// baseline (72.605 us; speedup 1.0000x reference)
//
#include <hip/hip_runtime.h>
#include <hip/hip_bf16.h>
#include <stdint.h>

typedef __bf16 bf16_t;
typedef __bf16 bf16x8 __attribute__((ext_vector_type(8)));
typedef float f32x4 __attribute__((ext_vector_type(4)));

#define L2E 1.44269504088896340736f

static __device__ __forceinline__ f32x4 mfma16(bf16x8 a, bf16x8 b, f32x4 c) {
  return __builtin_amdgcn_mfma_f32_16x16x32_bf16(a, b, c, 0, 0, 0);
}

static __device__ __forceinline__ void gload_lds16(const void* g, void* l) {
  __builtin_amdgcn_global_load_lds(
      (const __attribute__((address_space(1))) uint32_t*)g,
      (__attribute__((address_space(3))) uint32_t*)l, 16, 0, 0);
}

// ---------------- kernel 0: weights -> bf16, transposed to [proj][n=64][k=1024] ----
// proj 0 (Q) folds the 1/sqrt(64) scale.
__global__ __launch_bounds__(256) void wt_kernel(const float* __restrict__ Wq,
                                                 const float* __restrict__ Wk,
                                                 const float* __restrict__ Wv,
                                                 bf16_t* __restrict__ Wt) {
  int gid = blockIdx.x * 256 + threadIdx.x;  // 0 .. 196607
  int proj = gid >> 16;
  int rem = gid & 65535;          // = k*64 + n (row-major read, coalesced)
  int k = rem >> 6, n = rem & 63;
  const float* W = (proj == 0) ? Wq : (proj == 1) ? Wk : Wv;
  float v = W[rem];
  if (proj == 0) v *= 0.125f;
  Wt[proj * 65536 + n * 1024 + k] = (bf16_t)v;
}

// ---------------- kernel A: X f32 -> bf16 stream (memcpy-shaped READ probe) --------
// grid (1024, 3), block 256, grid-stride: every load instr = 1KB lane-contiguous
// float4; every store = 512B lane-contiguous bf16x4. Pure streaming — measures the
// achievable d_in read rate AND halves X bytes for the GEMM.
__global__ __launch_bounds__(256) void convert_kernel(
    const float* __restrict__ Xq, const float* __restrict__ Xk, const float* __restrict__ Xv,
    bf16_t* __restrict__ Xb) {
  int p = blockIdx.y;
  const float* X = (p == 0) ? Xq : (p == 1) ? Xk : Xv;
  bf16_t* dst = Xb + (size_t)p * 8388608;
  int tid = blockIdx.x * 256 + threadIdx.x;     // 0 .. 262143
#pragma unroll 8
  for (int i = 0; i < 8; ++i) {
    size_t e = (size_t)(i * 262144 + tid) * 4;  // float index, coalesced per instr
    float4 v = *(const float4*)(X + e);
    bf16_t o4[4] = {(bf16_t)v.x, (bf16_t)v.y, (bf16_t)v.z, (bf16_t)v.w};
    *(uint2*)(dst + e) = *(const uint2*)o4;
  }
}

// ---------------- kernel B: GEMM from bf16 Xb — W-in-LDS once, decoupled waves -----
// grid 256 (1/CU), block 384 (6 waves). Preamble: block's W[p] (128KB) -> LDS once
// (inverse-swizzled source, rule #21); one barrier total. Wave w independently does
// tile bid*6+w: A-frags = bf16x8 direct from Xb (16 full 64B lines/instr, 8-deep
// pipeline), W-frags = swizzled ds_read_b128. Straddle waves fall back to global W.
__global__ __launch_bounds__(384, 1) void gemm_kernel(
    const bf16_t* __restrict__ Xb, const bf16_t* __restrict__ Wt,
    bf16_t* __restrict__ Qb, bf16_t* __restrict__ Kb, bf16_t* __restrict__ Vt) {
  __shared__ alignas(16) char Wl[131072];        // W[p_lds]: [64 n][1024 k] bf16, swz
  __shared__ alignas(16) bf16_t Osm[6][16][72];  // per-wave output staging (padded)

  int tid = threadIdx.x;
  int w = tid / 64, lane = tid & 63;
  int l15 = lane & 15, g = lane >> 4;
  int bid = blockIdx.x;

  int p_lds = (bid * 6 + 2) >> 9;   // proj whose W goes to LDS (majority of waves)

  {
    const char* wb = (const char*)(Wt + (size_t)p_lds * 65536);
    for (int n = w; n < 64; n += 6) {
#pragma unroll
      for (int h = 0; h < 2; ++h) {
        const char* src = wb + n * 2048 + h * 1024 + ((lane * 16) ^ ((n & 7) << 4));
        gload_lds16(src, Wl + n * 2048 + h * 1024);
      }
    }
  }
  __syncthreads();   // drains vmcnt; the only block-wide barrier

  int T = bid * 6 + w;              // this wave's tile, < 1536
  int p = T >> 9;
  int t = T & 511;
  int m0 = t * 16;
  const bf16_t* xrow = Xb + (size_t)p * 8388608 + (size_t)(m0 + l15) * 1024 + g * 8;

  f32x4 acc[4] = {};

  auto wfrag_lds = [&](int ct, int byteoff) -> bf16x8 {
    int n = ct * 16 + l15;
    return *(const bf16x8*)(Wl + n * 2048 + (byteoff ^ ((n & 7) << 4)));
  };
  auto wfrag_glob = [&](int ct, int byteoff) -> bf16x8 {
    int n = ct * 16 + l15;
    return *(const bf16x8*)((const char*)(Wt + (size_t)p * 65536) + n * 2048 + byteoff);
  };

  auto run = [&](auto wf) {
    bf16x8 A0[8], A1[8];
    auto ldA = [&](int G, bf16x8* buf) {
#pragma unroll
      for (int i = 0; i < 8; ++i)
        buf[i] = *(const bf16x8*)(xrow + (G * 8 + i) * 32);
    };
    auto cmp = [&](int G, const bf16x8* buf) {
#pragma unroll
      for (int i = 0; i < 8; ++i) {
        int j = G * 8 + i;
#pragma unroll
        for (int ct = 0; ct < 4; ++ct)
          acc[ct] = mfma16(buf[i], wf(ct, j * 64 + g * 16), acc[ct]);
      }
    };
    ldA(0, A0);
    ldA(1, A1);
    cmp(0, A0);
    ldA(2, A0);
    cmp(1, A1);
    ldA(3, A1);
    cmp(2, A0);
    cmp(3, A1);
  };
  if (p == p_lds) run(wfrag_lds); else run(wfrag_glob);

  // ---- epilogue: per-wave staging -> coalesced stores ----
#pragma unroll
  for (int ct = 0; ct < 4; ++ct)
#pragma unroll
    for (int r = 0; r < 4; ++r)
      Osm[w][g * 4 + r][ct * 16 + l15] = (bf16_t)acc[ct][r];

  if (p < 2) {
    bf16_t* Ob = (p == 0) ? Qb : Kb;
    int row = lane >> 2, c0 = (lane & 3) * 16;
    uint4 v0 = *(const uint4*)&Osm[w][row][c0];
    uint4 v1 = *(const uint4*)&Osm[w][row][c0 + 8];
    *(uint4*)&Ob[(size_t)(m0 + row) * 64 + c0] = v0;
    *(uint4*)&Ob[(size_t)(m0 + row) * 64 + c0 + 8] = v1;
  } else {
    int d = lane;
    bf16_t tmp[16];
#pragma unroll
    for (int s = 0; s < 16; ++s) tmp[s] = Osm[w][s][d];
    int b = t >> 7, s0 = (t & 127) * 16;
    bf16_t* dst = Vt + ((size_t)(b * 64 + d)) * 2048 + s0;
    *(uint4*)dst = *(const uint4*)&tmp[0];
    *(uint4*)(dst + 8) = *(const uint4*)&tmp[8];
  }
}

// ---------------- kernel 2: causal flash attention, QBLK=32, KV-split 8 waves ------
#define NW 8
__global__ __launch_bounds__(512) void attn_kernel(
    const bf16_t* __restrict__ Qb, const bf16_t* __restrict__ Kb,
    const bf16_t* __restrict__ Vt, float* __restrict__ Out) {
  __shared__ alignas(16) char Psm[NW * 4096];   // per-wave 32x64 P tiles (swizzled)
  __shared__ float accL[NW][32][64];            // 64 KB
  __shared__ float mL[NW][32];
  __shared__ float lL[NW][32];

  int b = blockIdx.y;
  int x = blockIdx.x;
  int qt = (b >= 2) ? (63 - x) : x;    // pair heavy+light across CUs
  int q0 = qt * 32;
  int tid = threadIdx.x;
  int w = tid >> 6, lane = tid & 63;
  int l15 = lane & 15, g = lane >> 4;
  char* Pw = Psm + w * 4096;

  bf16x8 qf[2][2];
#pragma unroll
  for (int h = 0; h < 2; ++h) {
    size_t qrow = (size_t)(b * 2048 + q0 + h * 16 + l15) * 64;
    qf[h][0] = *(const bf16x8*)(Qb + qrow + g * 8);
    qf[h][1] = *(const bf16x8*)(Qb + qrow + 32 + g * 8);
  }

  float m_run[2][4], l_run[2][4];
  f32x4 acc_o[2][4] = {};
#pragma unroll
  for (int h = 0; h < 2; ++h)
#pragma unroll
    for (int r = 0; r < 4; ++r) { m_run[h][r] = -1e30f; l_run[h][r] = 0.f; }

  int ntiles = (q0 + 95) >> 6;         // ceil((q0+32)/64)
  const bf16_t* kbase = Kb + (size_t)b * 2048 * 64;
  const bf16_t* vbase = Vt + (size_t)b * 64 * 2048;

  for (int t = w; t < ntiles; t += NW) {
    int kv0 = t * 64;
    f32x4 s[2][4] = {};
#pragma unroll
    for (int ct = 0; ct < 4; ++ct) {
      const bf16_t* kr = kbase + (size_t)(kv0 + ct * 16 + l15) * 64 + g * 8;
      bf16x8 kf0 = *(const bf16x8*)kr;
      bf16x8 kf1 = *(const bf16x8*)(kr + 32);
#pragma unroll
      for (int h = 0; h < 2; ++h) {
        s[h][ct] = mfma16(qf[h][0], kf0, s[h][ct]);
        s[h][ct] = mfma16(qf[h][1], kf1, s[h][ct]);
      }
    }
    if (t == ntiles - 1) {  // diagonal tile: causal mask
#pragma unroll
      for (int h = 0; h < 2; ++h)
#pragma unroll
        for (int ct = 0; ct < 4; ++ct)
#pragma unroll
          for (int r = 0; r < 4; ++r) {
            int kg_ = kv0 + ct * 16 + l15;
            int qg_ = q0 + h * 16 + g * 4 + r;
            if (kg_ > qg_) s[h][ct][r] = -1e30f;
          }
    }

#pragma unroll
    for (int h = 0; h < 2; ++h)
#pragma unroll
      for (int r = 0; r < 4; ++r) {
        float mx = fmaxf(fmaxf(s[h][0][r], s[h][1][r]), fmaxf(s[h][2][r], s[h][3][r]));
        mx = fmaxf(mx, __shfl_xor(mx, 1, 64));
        mx = fmaxf(mx, __shfl_xor(mx, 2, 64));
        mx = fmaxf(mx, __shfl_xor(mx, 4, 64));
        mx = fmaxf(mx, __shfl_xor(mx, 8, 64));
        float mnew = fmaxf(m_run[h][r], mx);
        float scale = exp2f((m_run[h][r] - mnew) * L2E);
        m_run[h][r] = mnew;
        float ps = 0.f;
        int qrl = h * 16 + g * 4 + r;
        char* pb = Pw + qrl * 128;
        int swp = (qrl & 7) << 4;
#pragma unroll
        for (int ct = 0; ct < 4; ++ct) {
          float p = exp2f((s[h][ct][r] - mnew) * L2E);
          ps += p;
          *(bf16_t*)(pb + ((ct * 32 + l15 * 2) ^ swp)) = (bf16_t)p;
        }
        ps += __shfl_xor(ps, 1, 64);
        ps += __shfl_xor(ps, 2, 64);
        ps += __shfl_xor(ps, 4, 64);
        ps += __shfl_xor(ps, 8, 64);
        l_run[h][r] = l_run[h][r] * scale + ps;
#pragma unroll
        for (int dt = 0; dt < 4; ++dt) acc_o[h][dt][r] *= scale;
      }

    int swpr = (l15 & 7) << 4;
#pragma unroll
    for (int ks = 0; ks < 2; ++ks) {
      bf16x8 pf0 = *(const bf16x8*)(Pw + l15 * 128 + ((ks * 64 + g * 16) ^ swpr));
      bf16x8 pf1 = *(const bf16x8*)(Pw + (16 + l15) * 128 + ((ks * 64 + g * 16) ^ swpr));
#pragma unroll
      for (int dt = 0; dt < 4; ++dt) {
        const bf16_t* vr = vbase + (size_t)(dt * 16 + l15) * 2048 + kv0 + ks * 32 + g * 8;
        bf16x8 vf = *(const bf16x8*)vr;
        acc_o[0][dt] = mfma16(pf0, vf, acc_o[0][dt]);
        acc_o[1][dt] = mfma16(pf1, vf, acc_o[1][dt]);
      }
    }
  }

  if (l15 == 0) {
#pragma unroll
    for (int h = 0; h < 2; ++h)
#pragma unroll
      for (int r = 0; r < 4; ++r) {
        mL[w][h * 16 + g * 4 + r] = m_run[h][r];
        lL[w][h * 16 + g * 4 + r] = l_run[h][r];
      }
  }
#pragma unroll
  for (int h = 0; h < 2; ++h)
#pragma unroll
    for (int dt = 0; dt < 4; ++dt)
#pragma unroll
      for (int r = 0; r < 4; ++r)
        accL[w][h * 16 + g * 4 + r][dt * 16 + l15] = acc_o[h][dt][r];
  __syncthreads();

  int row = tid >> 4, c0 = (tid & 15) * 4;
  float M = -1e30f;
#pragma unroll
  for (int w2 = 0; w2 < NW; ++w2) M = fmaxf(M, mL[w2][row]);
  float L = 0.f;
  f32x4 o = {0.f, 0.f, 0.f, 0.f};
#pragma unroll
  for (int w2 = 0; w2 < NW; ++w2) {
    float sc = exp2f((mL[w2][row] - M) * L2E);
    L += lL[w2][row] * sc;
    f32x4 a = *(const f32x4*)&accL[w2][row][c0];
    o[0] += sc * a[0]; o[1] += sc * a[1]; o[2] += sc * a[2]; o[3] += sc * a[3];
  }
  float inv = 1.0f / L;
  float4 o4 = {o[0] * inv, o[1] * inv, o[2] * inv, o[3] * inv};
  *(float4*)&Out[(size_t)(b * 2048 + q0 + row) * 64 + c0] = o4;
}

extern "C" void kernel_launch(void* const* d_in, const int* in_sizes, int n_in,
                              void* d_out, int out_size, void* d_ws, size_t ws_size,
                              hipStream_t stream) {
  const float* Xk = (const float*)d_in[0];
  const float* Xv = (const float*)d_in[1];
  const float* Xq = (const float*)d_in[2];
  const float* Wq = (const float*)d_in[3];
  const float* Wk = (const float*)d_in[4];
  const float* Wv = (const float*)d_in[5];
  float* Out = (float*)d_out;

  bf16_t* ws = (bf16_t*)d_ws;
  bf16_t* Qb = ws;                 // [8192][64]   bf16, pre-scaled by 0.125
  bf16_t* Kb = ws + 524288;        // [8192][64]   bf16
  bf16_t* Vt = ws + 1048576;       // [4][64][2048] bf16 (V transposed)
  bf16_t* Wt = ws + 1572864;       // [3][64][1024] bf16 (weights transposed)
  bf16_t* Xb = ws + 2097152;       // [3][8192][1024] bf16 (X converted, 48 MB)

  wt_kernel<<<dim3(768), dim3(256), 0, stream>>>(Wq, Wk, Wv, Wt);
  convert_kernel<<<dim3(1024, 3), dim3(256), 0, stream>>>(Xq, Xk, Xv, Xb);
  gemm_kernel<<<dim3(256), dim3(384), 0, stream>>>(Xb, Wt, Qb, Kb, Vt);
  attn_kernel<<<dim3(64, 4), dim3(512), 0, stream>>>(Qb, Kb, Vt, Out);
}

// Round 14
// 55.264 us; speedup vs baseline: 1.3138x; 1.3138x over previous
//
#include <hip/hip_runtime.h>
#include <hip/hip_bf16.h>
#include <stdint.h>

typedef __bf16 bf16_t;
typedef __bf16 bf16x8 __attribute__((ext_vector_type(8)));
typedef float f32x4 __attribute__((ext_vector_type(4)));

#define L2E 1.44269504088896340736f

static __device__ __forceinline__ f32x4 mfma16(bf16x8 a, bf16x8 b, f32x4 c) {
  return __builtin_amdgcn_mfma_f32_16x16x32_bf16(a, b, c, 0, 0, 0);
}

static __device__ __forceinline__ float bf2f(uint16_t u) {
  union { uint32_t i; float f; } v; v.i = (uint32_t)u << 16; return v.f;
}

// stream-once read: non-temporal (no cache allocation). ext_vector type (not
// HIP_vector_type — the builtin rejects that).
static __device__ __forceinline__ f32x4 ldnt4(const float* p) {
  return __builtin_nontemporal_load((const f32x4*)p);
}

// ---------------- kernel 0: weights -> bf16, transposed to [proj][n=64][k=1024] ----
// proj 0 (Q) folds the 1/sqrt(64) scale.
__global__ __launch_bounds__(256) void wt_kernel(const float* __restrict__ Wq,
                                                 const float* __restrict__ Wk,
                                                 const float* __restrict__ Wv,
                                                 bf16_t* __restrict__ Wt) {
  int gid = blockIdx.x * 256 + threadIdx.x;  // 0 .. 196607
  int proj = gid >> 16;
  int rem = gid & 65535;          // = k*64 + n (row-major read, coalesced)
  int k = rem >> 6, n = rem & 63;
  const float* W = (proj == 0) ? Wq : (proj == 1) ? Wk : Wv;
  float v = W[rem];
  if (proj == 0) v *= 0.125f;
  Wt[proj * 65536 + n * 1024 + k] = (bf16_t)v;
}

// ---------------- kernel 1: QKV projection, W-in-registers, K-split 8 waves --------
// (r6 structure, best measured) + ONE change: X reads are NON-TEMPORAL.
__global__ __launch_bounds__(512) void proj_kernel(
    const float* __restrict__ Xq, const float* __restrict__ Xk, const float* __restrict__ Xv,
    const bf16_t* __restrict__ Wt,
    bf16_t* __restrict__ Qb, bf16_t* __restrict__ Kb, bf16_t* __restrict__ Vt) {
  __shared__ alignas(16) char Xl[8 * 4096];        // per-wave dbuf: 2 x 2KB bf16 tiles
  __shared__ alignas(16) bf16_t Msm[8][16][64];    // merge partials (bf16), 16 KB

  int tid = threadIdx.x;
  int w = tid >> 6, lane = tid & 63;
  int l15 = lane & 15, g = lane >> 4;
  char* myx = Xl + w * 4096;
  int kw = w;                                      // k-slice id

  bf16x8 Wf[4][4];                                 // [ct][s2]

  auto loadW = [&](int p) {
    const char* wb = (const char*)Wt + (size_t)p * 131072 + (size_t)kw * 256;
#pragma unroll
    for (int ct = 0; ct < 4; ++ct) {
#pragma unroll
      for (int i = 0; i < 4; ++i) {
        int n = i * 4 + (lane >> 4);
        int srcb = ((lane & 15) * 16) ^ ((n & 7) << 4);
        __builtin_amdgcn_global_load_lds(
            (const __attribute__((address_space(1))) uint32_t*)(wb + (size_t)(ct * 16 + n) * 2048 + srcb),
            (__attribute__((address_space(3))) uint32_t*)(myx + i * 1024), 16, 0, 0);
      }
      asm volatile("s_waitcnt vmcnt(0)" ::: "memory");
      __builtin_amdgcn_sched_barrier(0);
#pragma unroll
      for (int s2 = 0; s2 < 4; ++s2)
        Wf[ct][s2] = *(const bf16x8*)(myx + l15 * 256 + ((s2 * 64 + g * 16) ^ ((l15 & 7) << 4)));
      asm volatile("s_waitcnt lgkmcnt(0)" ::: "memory");
      __builtin_amdgcn_sched_barrier(0);
    }
  };

  f32x4 acc[4] = {};
  f32x4 xA[4], xB[4];

  auto issueX = [&](int t, int sub, f32x4* xr) {
    int p = t >> 9, lt = t & 511;
    const float* X = (p == 0) ? Xq : (p == 1) ? Xk : Xv;
    const float* base = X + (size_t)lt * 16384 + kw * 128 + sub * 64 + (lane & 15) * 4;
#pragma unroll
    for (int i = 0; i < 4; ++i)
      xr[i] = ldnt4(base + ((lane >> 4) + 4 * i) * 1024);   // NON-TEMPORAL
  };

  auto writeX = [&](const f32x4* xr, int sub) {
    char* buf = myx + sub * 2048;
#pragma unroll
    for (int i = 0; i < 4; ++i) {
      int rw = (lane >> 4) + 4 * i;
      bf16_t t4[4] = {(bf16_t)xr[i][0], (bf16_t)xr[i][1], (bf16_t)xr[i][2], (bf16_t)xr[i][3]};
      *(uint2*)(buf + rw * 128 + (((lane & 15) * 8) ^ ((rw & 7) << 4))) = *(const uint2*)t4;
    }
    asm volatile("s_waitcnt lgkmcnt(0)" ::: "memory");
    __builtin_amdgcn_sched_barrier(0);
  };

  auto computeX = [&](int sub) {
    const char* buf = myx + sub * 2048;
#pragma unroll
    for (int ks = 0; ks < 2; ++ks) {
      bf16x8 af = *(const bf16x8*)(buf + l15 * 128 + ((ks * 64 + g * 16) ^ ((l15 & 7) << 4)));
#pragma unroll
      for (int ct = 0; ct < 4; ++ct)
        acc[ct] = mfma16(af, Wf[ct][sub * 2 + ks], acc[ct]);
    }
  };

  int t0 = blockIdx.x * 3;
  int cur_p = t0 >> 9;
  loadW(cur_p);
  issueX(t0, 0, xA);

#pragma unroll 1
  for (int T = 0; T < 3; ++T) {
    int t = t0 + T;
    int p = t >> 9, lt = t & 511;
    if (p != cur_p) { loadW(p); cur_p = p; }
    issueX(t, 1, xB);
    writeX(xA, 0);
    computeX(0);
    if (T < 2) issueX(t + 1, 0, xA);
    writeX(xB, 1);
    computeX(1);

    // ---- 8-way k-merge + output ----
#pragma unroll
    for (int ct = 0; ct < 4; ++ct)
#pragma unroll
      for (int r = 0; r < 4; ++r)
        Msm[w][g * 4 + r][ct * 16 + l15] = (bf16_t)acc[ct][r];
#pragma unroll
    for (int ct = 0; ct < 4; ++ct) acc[ct] = (f32x4){0.f, 0.f, 0.f, 0.f};
    __syncthreads();

    int row = tid >> 5, c0 = (tid & 31) * 2;
    float s0 = 0.f, s1 = 0.f;
#pragma unroll
    for (int w2 = 0; w2 < 8; ++w2) {
      uint32_t u = *(const uint32_t*)&Msm[w2][row][c0];
      s0 += bf2f((uint16_t)u);
      s1 += bf2f((uint16_t)(u >> 16));
    }

    if (p < 2) {
      bf16_t* Ob = (p == 0) ? Qb : Kb;
      bf16_t o2[2] = {(bf16_t)s0, (bf16_t)s1};
      *(uint32_t*)&Ob[(size_t)(lt * 16 + row) * 64 + c0] = *(const uint32_t*)o2;
      __syncthreads();                       // protect Msm before next tile's writes
    } else {
      __syncthreads();                       // reduce-reads done -> overlay allowed
      bf16_t* Vsm = (bf16_t*)&Msm[0][0][0];  // [16 s][64 d], stride 72
      bf16_t o2[2] = {(bf16_t)s0, (bf16_t)s1};
      *(uint32_t*)&Vsm[row * 72 + c0] = *(const uint32_t*)o2;
      __syncthreads();
      if (tid < 128) {
        int d = tid >> 1, h = tid & 1;
        int b = lt >> 7;
        int s_ = (lt & 127) * 16 + h * 8;
        bf16_t tmp[8];
#pragma unroll
        for (int i = 0; i < 8; ++i) tmp[i] = Vsm[(h * 8 + i) * 72 + d];
        *(uint4*)(Vt + ((size_t)(b * 64 + d)) * 2048 + s_) = *(const uint4*)tmp;
      }
      __syncthreads();
    }
  }
}

// ---------------- kernel 2: causal flash attention, QBLK=32, KV-split 8 waves ------
#define NW 8
__global__ __launch_bounds__(512) void attn_kernel(
    const bf16_t* __restrict__ Qb, const bf16_t* __restrict__ Kb,
    const bf16_t* __restrict__ Vt, float* __restrict__ Out) {
  __shared__ alignas(16) char Psm[NW * 4096];   // per-wave 32x64 P tiles (swizzled)
  __shared__ float accL[NW][32][64];            // 64 KB
  __shared__ float mL[NW][32];
  __shared__ float lL[NW][32];

  int b = blockIdx.y;
  int x = blockIdx.x;
  int qt = (b >= 2) ? (63 - x) : x;    // pair heavy+light across CUs
  int q0 = qt * 32;
  int tid = threadIdx.x;
  int w = tid >> 6, lane = tid & 63;
  int l15 = lane & 15, g = lane >> 4;
  char* Pw = Psm + w * 4096;

  bf16x8 qf[2][2];
#pragma unroll
  for (int h = 0; h < 2; ++h) {
    size_t qrow = (size_t)(b * 2048 + q0 + h * 16 + l15) * 64;
    qf[h][0] = *(const bf16x8*)(Qb + qrow + g * 8);
    qf[h][1] = *(const bf16x8*)(Qb + qrow + 32 + g * 8);
  }

  float m_run[2][4], l_run[2][4];
  f32x4 acc_o[2][4] = {};
#pragma unroll
  for (int h = 0; h < 2; ++h)
#pragma unroll
    for (int r = 0; r < 4; ++r) { m_run[h][r] = -1e30f; l_run[h][r] = 0.f; }

  int ntiles = (q0 + 95) >> 6;         // ceil((q0+32)/64)
  const bf16_t* kbase = Kb + (size_t)b * 2048 * 64;
  const bf16_t* vbase = Vt + (size_t)b * 64 * 2048;

  for (int t = w; t < ntiles; t += NW) {
    int kv0 = t * 64;
    f32x4 s[2][4] = {};
#pragma unroll
    for (int ct = 0; ct < 4; ++ct) {
      const bf16_t* kr = kbase + (size_t)(kv0 + ct * 16 + l15) * 64 + g * 8;
      bf16x8 kf0 = *(const bf16x8*)kr;
      bf16x8 kf1 = *(const bf16x8*)(kr + 32);
#pragma unroll
      for (int h = 0; h < 2; ++h) {
        s[h][ct] = mfma16(qf[h][0], kf0, s[h][ct]);
        s[h][ct] = mfma16(qf[h][1], kf1, s[h][ct]);
      }
    }
    if (t == ntiles - 1) {  // diagonal tile: causal mask
#pragma unroll
      for (int h = 0; h < 2; ++h)
#pragma unroll
        for (int ct = 0; ct < 4; ++ct)
#pragma unroll
          for (int r = 0; r < 4; ++r) {
            int kg_ = kv0 + ct * 16 + l15;
            int qg_ = q0 + h * 16 + g * 4 + r;
            if (kg_ > qg_) s[h][ct][r] = -1e30f;
          }
    }

#pragma unroll
    for (int h = 0; h < 2; ++h)
#pragma unroll
      for (int r = 0; r < 4; ++r) {
        float mx = fmaxf(fmaxf(s[h][0][r], s[h][1][r]), fmaxf(s[h][2][r], s[h][3][r]));
        mx = fmaxf(mx, __shfl_xor(mx, 1, 64));
        mx = fmaxf(mx, __shfl_xor(mx, 2, 64));
        mx = fmaxf(mx, __shfl_xor(mx, 4, 64));
        mx = fmaxf(mx, __shfl_xor(mx, 8, 64));
        float mnew = fmaxf(m_run[h][r], mx);
        float scale = exp2f((m_run[h][r] - mnew) * L2E);
        m_run[h][r] = mnew;
        float ps = 0.f;
        int qrl = h * 16 + g * 4 + r;
        char* pb = Pw + qrl * 128;
        int swp = (qrl & 7) << 4;
#pragma unroll
        for (int ct = 0; ct < 4; ++ct) {
          float p = exp2f((s[h][ct][r] - mnew) * L2E);
          ps += p;
          *(bf16_t*)(pb + ((ct * 32 + l15 * 2) ^ swp)) = (bf16_t)p;
        }
        ps += __shfl_xor(ps, 1, 64);
        ps += __shfl_xor(ps, 2, 64);
        ps += __shfl_xor(ps, 4, 64);
        ps += __shfl_xor(ps, 8, 64);
        l_run[h][r] = l_run[h][r] * scale + ps;
#pragma unroll
        for (int dt = 0; dt < 4; ++dt) acc_o[h][dt][r] *= scale;
      }

    int swpr = (l15 & 7) << 4;
#pragma unroll
    for (int ks = 0; ks < 2; ++ks) {
      bf16x8 pf0 = *(const bf16x8*)(Pw + l15 * 128 + ((ks * 64 + g * 16) ^ swpr));
      bf16x8 pf1 = *(const bf16x8*)(Pw + (16 + l15) * 128 + ((ks * 64 + g * 16) ^ swpr));
#pragma unroll
      for (int dt = 0; dt < 4; ++dt) {
        const bf16_t* vr = vbase + (size_t)(dt * 16 + l15) * 2048 + kv0 + ks * 32 + g * 8;
        bf16x8 vf = *(const bf16x8*)vr;
        acc_o[0][dt] = mfma16(pf0, vf, acc_o[0][dt]);
        acc_o[1][dt] = mfma16(pf1, vf, acc_o[1][dt]);
      }
    }
  }

  if (l15 == 0) {
#pragma unroll
    for (int h = 0; h < 2; ++h)
#pragma unroll
      for (int r = 0; r < 4; ++r) {
        mL[w][h * 16 + g * 4 + r] = m_run[h][r];
        lL[w][h * 16 + g * 4 + r] = l_run[h][r];
      }
  }
#pragma unroll
  for (int h = 0; h < 2; ++h)
#pragma unroll
    for (int dt = 0; dt < 4; ++dt)
#pragma unroll
      for (int r = 0; r < 4; ++r)
        accL[w][h * 16 + g * 4 + r][dt * 16 + l15] = acc_o[h][dt][r];
  __syncthreads();

  int row = tid >> 4, c0 = (tid & 15) * 4;
  float M = -1e30f;
#pragma unroll
  for (int w2 = 0; w2 < NW; ++w2) M = fmaxf(M, mL[w2][row]);
  float L = 0.f;
  f32x4 o = {0.f, 0.f, 0.f, 0.f};
#pragma unroll
  for (int w2 = 0; w2 < NW; ++w2) {
    float sc = exp2f((mL[w2][row] - M) * L2E);
    L += lL[w2][row] * sc;
    f32x4 a = *(const f32x4*)&accL[w2][row][c0];
    o[0] += sc * a[0]; o[1] += sc * a[1]; o[2] += sc * a[2]; o[3] += sc * a[3];
  }
  float inv = 1.0f / L;
  float4 o4 = {o[0] * inv, o[1] * inv, o[2] * inv, o[3] * inv};
  *(float4*)&Out[(size_t)(b * 2048 + q0 + row) * 64 + c0] = o4;
}

extern "C" void kernel_launch(void* const* d_in, const int* in_sizes, int n_in,
                              void* d_out, int out_size, void* d_ws, size_t ws_size,
                              hipStream_t stream) {
  const float* Xk = (const float*)d_in[0];
  const float* Xv = (const float*)d_in[1];
  const float* Xq = (const float*)d_in[2];
  const float* Wq = (const float*)d_in[3];
  const float* Wk = (const float*)d_in[4];
  const float* Wv = (const float*)d_in[5];
  float* Out = (float*)d_out;

  bf16_t* ws = (bf16_t*)d_ws;
  bf16_t* Qb = ws;                 // [8192][64]   bf16, pre-scaled by 0.125
  bf16_t* Kb = ws + 524288;        // [8192][64]   bf16
  bf16_t* Vt = ws + 1048576;       // [4][64][2048] bf16 (V transposed)
  bf16_t* Wt = ws + 1572864;       // [3][64][1024] bf16 (weights transposed)

  wt_kernel<<<dim3(768), dim3(256), 0, stream>>>(Wq, Wk, Wv, Wt);
  proj_kernel<<<dim3(512), dim3(512), 0, stream>>>(Xq, Xk, Xv, Wt, Qb, Kb, Vt);
  attn_kernel<<<dim3(64, 4), dim3(512), 0, stream>>>(Qb, Kb, Vt, Out);
}